// Round 11
// baseline (170.650 us; speedup 1.0000x reference)
//
#include <hip/hip_runtime.h>
#include <math.h>

using f32x4   = __attribute__((ext_vector_type(4))) float;
using f32x16  = __attribute__((ext_vector_type(16))) float;
using bf16x8  = __attribute__((ext_vector_type(8))) short;

constexpr int Bb = 2;
constexpr int T  = 2048;
constexpr int D  = 768;
constexpr int H  = 12;
constexpr int Dh = 64;
constexpr int M  = Bb * T;        // 4096
constexpr int NQKV = 3 * D;       // 2304
// fold 1/sqrt(Dh) * log2(e) into Q so attention uses exp2 directly
#define SCALE_Q 0.18033688011112042f

#define Z16 (f32x16){0.f,0.f,0.f,0.f,0.f,0.f,0.f,0.f,0.f,0.f,0.f,0.f,0.f,0.f,0.f,0.f}

// ---------------------------------------------------------------------------
// helpers
// ---------------------------------------------------------------------------
__device__ __forceinline__ unsigned short f2bf(float f) {
    unsigned u = __float_as_uint(f);
    u += 0x7fffu + ((u >> 16) & 1u);      // RNE
    return (unsigned short)(u >> 16);
}

__device__ __forceinline__ ushort4 f2bf4(float4 f) {
    return make_ushort4(f2bf(f.x), f2bf(f.y), f2bf(f.z), f2bf(f.w));
}

// truncate-pack two fp32 -> packed bf16x2 in ONE v_perm_b32:
// result = { hi16(hi_f), hi16(lo_f) }
__device__ __forceinline__ unsigned permpk(float hi_f, float lo_f) {
    return __builtin_amdgcn_perm(__float_as_uint(hi_f), __float_as_uint(lo_f),
                                 0x07060302u);
}

// async global->LDS, 16B per lane; lds base must be wave-uniform (HW scatters
// lane l's data to base + l*16)
__device__ __forceinline__ void async_copy16(const void* g, void* lds_base) {
    __builtin_amdgcn_global_load_lds(
        (const __attribute__((address_space(1))) unsigned int*)g,
        (__attribute__((address_space(3))) unsigned int*)lds_base, 16, 0, 0);
}

// ---------------------------------------------------------------------------
// Prep: fp32 -> bf16 for X, stacked Wqkv, Wo; stack biases (fp32)
// ---------------------------------------------------------------------------
__global__ __launch_bounds__(256) void prep_kernel(
    const float4* __restrict__ x,
    const float4* __restrict__ Wq, const float4* __restrict__ Wk,
    const float4* __restrict__ Wv, const float4* __restrict__ Wo,
    const float* __restrict__ bq, const float* __restrict__ bk, const float* __restrict__ bv,
    ushort4* __restrict__ Xb, ushort4* __restrict__ Wqkvb, ushort4* __restrict__ Wob,
    float* __restrict__ biasS)
{
    const int stride = gridDim.x * 256;
    const int i0 = blockIdx.x * 256 + threadIdx.x;
    const int NX = M * D / 4;       // 786432
    const int NW = D * D / 4;       // 147456
    for (int i = i0; i < NX; i += stride) Xb[i] = f2bf4(x[i]);
    for (int i = i0; i < NW; i += stride) {
        Wqkvb[i]          = f2bf4(Wq[i]);
        Wqkvb[NW + i]     = f2bf4(Wk[i]);
        Wqkvb[2 * NW + i] = f2bf4(Wv[i]);
        Wob[i]            = f2bf4(Wo[i]);
    }
    for (int i = i0; i < D; i += stride) {
        biasS[i]         = bq[i];
        biasS[D + i]     = bk[i];
        biasS[2 * D + i] = bv[i];
    }
}

// ---------------------------------------------------------------------------
// bf16 GEMM (B^T layout): C[m,n] = sum_k A[m,k] * B[n,k] + bias[n]
// TM x 128 tile, BK=64 (128 B rows = 8 x 16B blocks), 256 threads (4 waves),
// 16x16x32 MFMA. LDS rows XOR-swizzled (slot = blk ^ (row&7)) -> fragment
// ds_read_b128 are conflict-free.
// Config search CLOSED (measured): QKV = TM=128/DB=0; out-proj = TM=32/DB=1.
// XCD-locality swizzle: groups of 8 consecutive linear block IDs share the
// same col-tile. (gridDim.y must be a multiple of 8.)
// MODE 0: fp32 out [M, Ndim] row-major
// MODE 1: QKV epilogue -> bf16 Q,K head-split [B,H,T,Dh] (Q pre-scaled by
//         SCALE_Q); V written TRANSPOSED [B,H,Dh,T] with key index
//         bit-2<->bit-3 swapped (tp = swap bits 2,3 of t) to match the attn
//         32x32 MFMA P-fragment k-slot order (derived: sigma(s)=a(f,j,hs)).
// ---------------------------------------------------------------------------
template <int MODE, int TM, int DB>
__global__ __launch_bounds__(256) void gemm_bt_kernel(
    const unsigned short* __restrict__ A, const unsigned short* __restrict__ Bm,
    const float* __restrict__ bias, const int Kdim, const int Ndim,
    float* __restrict__ Cout,
    unsigned short* __restrict__ Qo, unsigned short* __restrict__ Ko,
    unsigned short* __restrict__ Vo)
{
    constexpr int IW  = TM / 32;           // acc row-frags per wave
    constexpr int NCH = (TM + 128) / 8;    // 1 KB staging chunks (8 rows each)
    constexpr int TB  = (TM + 128) * 128;  // bytes per LDS buffer
    __shared__ unsigned short Sm[(TM + 128) * 64 * (DB ? 2 : 1)];
    const int tid  = threadIdx.x;
    const int lane = tid & 63, wv = tid >> 6;
    const int l15  = lane & 15, l4 = lane >> 4;
    const int wr   = wv >> 1,  wc = wv & 1;

    // swizzle (gridDim.y must be a multiple of 8)
    const int lin = blockIdx.y * gridDim.x + blockIdx.x;
    const int gx  = (lin >> 3) % gridDim.x;
    const int gy  = (lin / (8 * gridDim.x)) * 8 + (lin & 7);
    const int row0 = gy * TM, col0 = gx * 128;

    auto stage = [&](int k0, int b) {
        #pragma unroll
        for (int ch0 = 0; ch0 < NCH; ch0 += 4) {   // NCH % 4 == 0
            const int ch = ch0 + wv;           // wave-uniform per call
            const int offb = ch * 1024;
            const int off  = offb + lane * 16;
            const int r  = off >> 7;           // row in [0, TM+128)
            const int bl = (off & 127) >> 4;   // 16B block within 128 B row
            const int gc = (bl ^ (r & 7)) << 3;    // swizzled element col
            const unsigned short* src = (r < TM)
                ? A  + (size_t)(row0 + r) * Kdim + k0 + gc
                : Bm + (size_t)(col0 + (r - TM)) * Kdim + k0 + gc;
            async_copy16(src, (char*)Sm + b * TB + offb);
        }
    };

    f32x4 acc[IW][4];
    #pragma unroll
    for (int i = 0; i < IW; ++i)
        #pragma unroll
        for (int j = 0; j < 4; ++j)
            acc[i][j] = (f32x4){0.f, 0.f, 0.f, 0.f};

    if (DB) stage(0, 0);

    for (int k0 = 0, it = 0; k0 < Kdim; k0 += 64, ++it) {
        const int cur = DB ? (it & 1) : 0;
        __syncthreads();                 // DB=0: prev ds_reads done.
                                         // DB=1: buf[cur] staged (vmcnt drain)
                                         //       + buf[cur^1] readers done.
        if (DB) {
            if (k0 + 64 < Kdim) stage(k0 + 64, cur ^ 1);
        } else {
            stage(k0, 0);
            __syncthreads();             // drains vmcnt -> tiles ready
        }
        const char* Sb_ = (const char*)Sm + cur * TB;

        #pragma unroll
        for (int c = 0; c < 2; ++c) {          // k halves of the 64-wide tile
            bf16x8 af[IW], bfr[4];
            #pragma unroll
            for (int i = 0; i < IW; ++i) {
                const int row = wr * (TM / 2) + i * 16 + l15;
                af[i] = *(const bf16x8*)(Sb_ +
                        row * 128 + (((c << 2) + l4) ^ (row & 7)) * 16);
            }
            #pragma unroll
            for (int j = 0; j < 4; ++j) {
                const int row = TM + wc * 64 + j * 16 + l15;
                bfr[j] = *(const bf16x8*)(Sb_ +
                        row * 128 + (((c << 2) + l4) ^ (row & 7)) * 16);
            }
            #pragma unroll
            for (int i = 0; i < IW; ++i)
                #pragma unroll
                for (int j = 0; j < 4; ++j)
                    acc[i][j] = __builtin_amdgcn_mfma_f32_16x16x32_bf16(af[i], bfr[j], acc[i][j], 0, 0, 0);
        }
    }

    // C/D layout: col = lane&15, row = (lane>>4)*4 + reg
    if (MODE == 0) {
        #pragma unroll
        for (int j = 0; j < 4; ++j) {
            const int n = col0 + wc * 64 + j * 16 + l15;
            const float bv_ = bias[n];
            #pragma unroll
            for (int i = 0; i < IW; ++i) {
                #pragma unroll
                for (int r = 0; r < 4; ++r) {
                    const int m = row0 + wr * (TM / 2) + i * 16 + l4 * 4 + r;
                    Cout[(size_t)m * Ndim + n] = acc[i][j][r] + bv_;
                }
            }
        }
    } else {
        #pragma unroll
        for (int j = 0; j < 4; ++j) {
            const int n = col0 + wc * 64 + j * 16 + l15;
            const int which = n / D;           // uniform per block (768 % 128 == 0)
            const int hd = n % D;
            const int h = hd >> 6, d = hd & 63;
            const float bv_ = bias[n];
            if (which == 2) {
                // V transposed [B,H,Dh,T], key index with bits 2,3 swapped
                // (matches attn 32x32 P-fragment slot order; t multiple of 4
                // here so bits 0,1 are carried by the ushort4 elements)
                #pragma unroll
                for (int i = 0; i < IW; ++i) {
                    const int m0 = row0 + wr * (TM / 2) + i * 16 + l4 * 4;
                    const int b = m0 >> 11, t = m0 & (T - 1);
                    const int tp = (t & ~12) | ((t & 4) << 1) | ((t & 8) >> 1);
                    float4 v4;
                    v4.x = acc[i][j][0] + bv_; v4.y = acc[i][j][1] + bv_;
                    v4.z = acc[i][j][2] + bv_; v4.w = acc[i][j][3] + bv_;
                    *(ushort4*)&Vo[((size_t)(b * H + h) * Dh + d) * T + tp] = f2bf4(v4);
                }
            } else {
                const float scale = (which == 0) ? SCALE_Q : 1.0f;
                unsigned short* dst = (which == 0) ? Qo : Ko;
                #pragma unroll
                for (int i = 0; i < IW; ++i) {
                    #pragma unroll
                    for (int r = 0; r < 4; ++r) {
                        const int m = row0 + wr * (TM / 2) + i * 16 + l4 * 4 + r;
                        const int b = m >> 11, t = m & (T - 1);
                        dst[((size_t)(b * H + h) * T + t) * Dh + d] =
                            f2bf((acc[i][j][r] + bv_) * scale);
                    }
                }
            }
        }
    }
}

// ---------------------------------------------------------------------------
// Flash attention — 32x32x16 MFMA decomposition.
// Evidence chain: attn is ISSUE-RATE bound (R8: invariant to waves 12->20/CU;
// R3: worse at 6; R10: address-VALU hoist neutral). 32x32 shape halves the
// per-work instruction stream: one wave = 32 q x 64 keys per tile with
// 16 b128 reads + 20 MFMAs (8 QK^T + 8 PV + 4 ones) — the 16x16 version
// spent 16 reads + 18 MFMAs on HALF the q.
// Layouts (derived + symbolically checked):
//   QK^T: S^T = mfma32(A=K[key=l31][dh=c*16+hs*8+j], B=Q[q=l31][same dh]).
//   S^T C/D: col=q=lane&31, row=key=(reg&3)+8*(reg>>2)+4*hs  -> q stays
//   lane-resident; P packs reg-ascending into A-frags with NO cross-lane.
//   The induced P k-slot order requires V's key storage permuted by
//   tp = t with bits 2,3 swapped (written that way by the GEMM epilogue).
//   PV: O = mfma32(A=P, B=V^T[dh=h2*32+l31][keys m*16+hs*8+j]).
// 2 waves/block (128 thr), QBLK=64 -> grid (32,24)=768, 32 KB LDS ->
// 5 blocks/CU = 10 waves/CU at ~half the per-wave issue.
// Bank aliasing per 16-lane phase is 2-way (free), same as the proven
// kernel's measured 0 conflicts.
// Failed directions (do not retry): wave K-split (R1), QBLK=128@256thr (R3),
// K-from-global (R4/R5), KV-split+combine (R8), addr-hoist (R10, neutral).
// ---------------------------------------------------------------------------
__global__ __launch_bounds__(128) void attn_kernel(
    const unsigned short* __restrict__ Q, const unsigned short* __restrict__ Kg,
    const unsigned short* __restrict__ Vt, unsigned short* __restrict__ Ctx)
{
    __shared__ unsigned short Ks[2][64 * 64];
    __shared__ unsigned short Vs[2][64 * 64];
    const int bh = blockIdx.y;
    const int q0 = blockIdx.x * 64;
    const int tid = threadIdx.x, lane = tid & 63, wv = tid >> 6;   // 2 waves
    const int l31 = lane & 31, hs = lane >> 5;
    const unsigned short* Qp = Q  + (size_t)bh * T * Dh;
    const unsigned short* Kp = Kg + (size_t)bh * T * Dh;
    const unsigned short* Vp = Vt + (size_t)bh * Dh * T;

    // Q fragments (B-operand): col=q = q0+wv*32+l31, k(dh) = c*16 + hs*8 + j
    bf16x8 qf[4];
    #pragma unroll
    for (int c = 0; c < 4; ++c)
        qf[c] = *(const bf16x8*)&Qp[(size_t)(q0 + wv * 32 + l31) * Dh + c * 16 + hs * 8];

    const short oneb = (short)0x3F80;     // bf16 1.0
    const bf16x8 onesf = {oneb, oneb, oneb, oneb, oneb, oneb, oneb, oneb};

    auto load_tiles = [&](int kt, int buf) {
        #pragma unroll
        for (int i = 0; i < 4; ++i) {
            const int offb = wv * 4096 + i * 1024;
            const int off  = offb + lane * 16;
            const int r = off >> 7;                     // 128 B per row
            const int blk = (off & 127) >> 4;
            const int gc = (blk ^ (r & 7)) << 3;        // swizzled element col
            async_copy16(Kp + (size_t)(kt + r) * Dh + gc, (char*)&Ks[buf][0] + offb);
            async_copy16(Vp + (size_t)r * T + kt + gc,    (char*)&Vs[buf][0] + offb);
        }
    };

    load_tiles(0, 0);
    f32x16 o[2], oL;
    o[0] = Z16; o[1] = Z16; oL = Z16;

    for (int kt64 = 0; kt64 < T / 64; ++kt64) {
        const int cur = kt64 & 1;
        __syncthreads();     // K/V(kt64) ready (vmcnt drain); buf cur^1 reads done
        if (kt64 + 1 < T / 64) load_tiles((kt64 + 1) * 64, cur ^ 1);

        const char* Kb = (const char*)&Ks[cur][0];
        const char* Vb = (const char*)&Vs[cur][0];

        // ---- S^T group 0 (keys 0..31): rows l31 ----
        f32x16 S0 = Z16;
        #pragma unroll
        for (int c = 0; c < 4; ++c) {
            const int row = l31;
            bf16x8 kb = *(const bf16x8*)(Kb + row * 128 + (((c << 1) + hs) ^ (row & 7)) * 16);
            S0 = __builtin_amdgcn_mfma_f32_32x32x16_bf16(kb, qf[c], S0, 0, 0, 0);
        }
        #pragma unroll
        for (int r = 0; r < 16; ++r)
            S0[r] = __builtin_amdgcn_exp2f(S0[r]);
        union { unsigned u[4]; bf16x8 v; } pa0, pa1;
        pa0.u[0] = permpk(S0[1],  S0[0]);  pa0.u[1] = permpk(S0[3],  S0[2]);
        pa0.u[2] = permpk(S0[5],  S0[4]);  pa0.u[3] = permpk(S0[7],  S0[6]);
        pa1.u[0] = permpk(S0[9],  S0[8]);  pa1.u[1] = permpk(S0[11], S0[10]);
        pa1.u[2] = permpk(S0[13], S0[12]); pa1.u[3] = permpk(S0[15], S0[14]);

        // ---- S^T group 1 (keys 32..63): rows 32 + l31 ----
        f32x16 S1 = Z16;
        #pragma unroll
        for (int c = 0; c < 4; ++c) {
            const int row = 32 + l31;
            bf16x8 kb = *(const bf16x8*)(Kb + row * 128 + (((c << 1) + hs) ^ (row & 7)) * 16);
            S1 = __builtin_amdgcn_mfma_f32_32x32x16_bf16(kb, qf[c], S1, 0, 0, 0);
        }

        // ---- PV m=0,1 (+ones) — overlaps exp2 of group 1 ----
        oL = __builtin_amdgcn_mfma_f32_32x32x16_bf16(pa0.v, onesf, oL, 0, 0, 0);
        oL = __builtin_amdgcn_mfma_f32_32x32x16_bf16(pa1.v, onesf, oL, 0, 0, 0);
        #pragma unroll
        for (int h2 = 0; h2 < 2; ++h2) {
            const int row = h2 * 32 + l31;
            bf16x8 v0 = *(const bf16x8*)(Vb + row * 128 + ((0 + hs) ^ (row & 7)) * 16);
            o[h2] = __builtin_amdgcn_mfma_f32_32x32x16_bf16(pa0.v, v0, o[h2], 0, 0, 0);
            bf16x8 v1 = *(const bf16x8*)(Vb + row * 128 + ((2 + hs) ^ (row & 7)) * 16);
            o[h2] = __builtin_amdgcn_mfma_f32_32x32x16_bf16(pa1.v, v1, o[h2], 0, 0, 0);
        }

        #pragma unroll
        for (int r = 0; r < 16; ++r)
            S1[r] = __builtin_amdgcn_exp2f(S1[r]);
        union { unsigned u[4]; bf16x8 v; } pa2, pa3;
        pa2.u[0] = permpk(S1[1],  S1[0]);  pa2.u[1] = permpk(S1[3],  S1[2]);
        pa2.u[2] = permpk(S1[5],  S1[4]);  pa2.u[3] = permpk(S1[7],  S1[6]);
        pa3.u[0] = permpk(S1[9],  S1[8]);  pa3.u[1] = permpk(S1[11], S1[10]);
        pa3.u[2] = permpk(S1[13], S1[12]); pa3.u[3] = permpk(S1[15], S1[14]);

        // ---- PV m=2,3 (+ones) ----
        oL = __builtin_amdgcn_mfma_f32_32x32x16_bf16(pa2.v, onesf, oL, 0, 0, 0);
        oL = __builtin_amdgcn_mfma_f32_32x32x16_bf16(pa3.v, onesf, oL, 0, 0, 0);
        #pragma unroll
        for (int h2 = 0; h2 < 2; ++h2) {
            const int row = h2 * 32 + l31;
            bf16x8 v2 = *(const bf16x8*)(Vb + row * 128 + ((4 + hs) ^ (row & 7)) * 16);
            o[h2] = __builtin_amdgcn_mfma_f32_32x32x16_bf16(pa2.v, v2, o[h2], 0, 0, 0);
            bf16x8 v3 = *(const bf16x8*)(Vb + row * 128 + ((6 + hs) ^ (row & 7)) * 16);
            o[h2] = __builtin_amdgcn_mfma_f32_32x32x16_bf16(pa3.v, v3, o[h2], 0, 0, 0);
        }
    }

    // normalize, write ctx bf16 [B, T, D]
    // O C/D: col = dh_within_half = l31, row = q = (reg&3)+8*(reg>>2)+4*hs
    const int b = bh / H, h = bh % H;
    #pragma unroll
    for (int reg = 0; reg < 16; ++reg) {
        const float inv = 1.0f / oL[reg];
        const int t = q0 + wv * 32 + (reg & 3) + 8 * (reg >> 2) + 4 * hs;
        #pragma unroll
        for (int h2 = 0; h2 < 2; ++h2) {
            const int col = h * 64 + h2 * 32 + l31;
            Ctx[(size_t)(b * T + t) * D + col] = f2bf(o[h2][reg] * inv);
        }
    }
}

// ---------------------------------------------------------------------------
extern "C" void kernel_launch(void* const* d_in, const int* in_sizes, int n_in,
                              void* d_out, int out_size, void* d_ws, size_t ws_size,
                              hipStream_t stream) {
    const float* x  = (const float*)d_in[0];
    const float* Wq = (const float*)d_in[1];
    const float* bq = (const float*)d_in[2];
    const float* Wk = (const float*)d_in[3];
    const float* bk = (const float*)d_in[4];
    const float* Wv = (const float*)d_in[5];
    const float* bv = (const float*)d_in[6];
    const float* Wo = (const float*)d_in[7];
    const float* bo = (const float*)d_in[8];
    float* out = (float*)d_out;

    // workspace carve-up (~34 MB total)
    char* w = (char*)d_ws;
    auto alloc = [&](size_t bytes) {
        char* p = w; w += (bytes + 255) & ~(size_t)255; return p;
    };
    unsigned short* Xb    = (unsigned short*)alloc((size_t)M * D * 2);
    unsigned short* Wqkvb = (unsigned short*)alloc((size_t)NQKV * D * 2);
    unsigned short* Wob   = (unsigned short*)alloc((size_t)D * D * 2);
    float*          biasS = (float*)alloc((size_t)NQKV * 4);
    unsigned short* Qb    = (unsigned short*)alloc((size_t)M * D * 2);
    unsigned short* Kb    = (unsigned short*)alloc((size_t)M * D * 2);
    unsigned short* Vtb   = (unsigned short*)alloc((size_t)M * D * 2);
    unsigned short* Ctxb  = (unsigned short*)alloc((size_t)M * D * 2);

    prep_kernel<<<1024, 256, 0, stream>>>(
        (const float4*)x, (const float4*)Wq, (const float4*)Wk, (const float4*)Wv,
        (const float4*)Wo, bq, bk, bv,
        (ushort4*)Xb, (ushort4*)Wqkvb, (ushort4*)Wob, biasS);

    // QKV GEMM: TM=128, DB=0 (best measured)
    gemm_bt_kernel<1, 128, 0><<<dim3(NQKV / 128, M / 128), 256, 0, stream>>>(
        Xb, Wqkvb, biasS, D, NQKV, nullptr, Qb, Kb, Vtb);

    // attention: 32x32 MFMA, 128 threads (2 waves x 32 q), grid (32,24)=768
    attn_kernel<<<dim3(T / 64, Bb * H), 128, 0, stream>>>(Qb, Kb, Vtb, Ctxb);

    // out-projection: TM=32 + DB=1 (best measured, R6)
    gemm_bt_kernel<0, 32, 1><<<dim3(D / 128, M / 32), 256, 0, stream>>>(
        Ctxb, Wob, bo, D, D, out, nullptr, nullptr, nullptr);
}

// Round 12
// 156.257 us; speedup vs baseline: 1.0921x; 1.0921x over previous
//
#include <hip/hip_runtime.h>
#include <math.h>

using f32x4   = __attribute__((ext_vector_type(4))) float;
using bf16x8  = __attribute__((ext_vector_type(8))) short;

constexpr int Bb = 2;
constexpr int T  = 2048;
constexpr int D  = 768;
constexpr int H  = 12;
constexpr int Dh = 64;
constexpr int M  = Bb * T;        // 4096
constexpr int NQKV = 3 * D;       // 2304
// fold 1/sqrt(Dh) * log2(e) into Q so attention uses exp2 directly
#define SCALE_Q 0.18033688011112042f

// ---------------------------------------------------------------------------
// helpers
// ---------------------------------------------------------------------------
__device__ __forceinline__ unsigned short f2bf(float f) {
    unsigned u = __float_as_uint(f);
    u += 0x7fffu + ((u >> 16) & 1u);      // RNE
    return (unsigned short)(u >> 16);
}

__device__ __forceinline__ ushort4 f2bf4(float4 f) {
    return make_ushort4(f2bf(f.x), f2bf(f.y), f2bf(f.z), f2bf(f.w));
}

// truncate-pack two fp32 -> packed bf16x2 in ONE v_perm_b32:
// result = { hi16(hi_f), hi16(lo_f) }
__device__ __forceinline__ unsigned permpk(float hi_f, float lo_f) {
    return __builtin_amdgcn_perm(__float_as_uint(hi_f), __float_as_uint(lo_f),
                                 0x07060302u);
}

// async global->LDS, 16B per lane; lds base must be wave-uniform (HW scatters
// lane l's data to base + l*16)
__device__ __forceinline__ void async_copy16(const void* g, void* lds_base) {
    __builtin_amdgcn_global_load_lds(
        (const __attribute__((address_space(1))) unsigned int*)g,
        (__attribute__((address_space(3))) unsigned int*)lds_base, 16, 0, 0);
}

// ---------------------------------------------------------------------------
// Prep: fp32 -> bf16 for X, stacked Wqkv, Wo; stack biases (fp32)
// ---------------------------------------------------------------------------
__global__ __launch_bounds__(256) void prep_kernel(
    const float4* __restrict__ x,
    const float4* __restrict__ Wq, const float4* __restrict__ Wk,
    const float4* __restrict__ Wv, const float4* __restrict__ Wo,
    const float* __restrict__ bq, const float* __restrict__ bk, const float* __restrict__ bv,
    ushort4* __restrict__ Xb, ushort4* __restrict__ Wqkvb, ushort4* __restrict__ Wob,
    float* __restrict__ biasS)
{
    const int stride = gridDim.x * 256;
    const int i0 = blockIdx.x * 256 + threadIdx.x;
    const int NX = M * D / 4;       // 786432
    const int NW = D * D / 4;       // 147456
    for (int i = i0; i < NX; i += stride) Xb[i] = f2bf4(x[i]);
    for (int i = i0; i < NW; i += stride) {
        Wqkvb[i]          = f2bf4(Wq[i]);
        Wqkvb[NW + i]     = f2bf4(Wk[i]);
        Wqkvb[2 * NW + i] = f2bf4(Wv[i]);
        Wob[i]            = f2bf4(Wo[i]);
    }
    for (int i = i0; i < D; i += stride) {
        biasS[i]         = bq[i];
        biasS[D + i]     = bk[i];
        biasS[2 * D + i] = bv[i];
    }
}

// ---------------------------------------------------------------------------
// bf16 GEMM (B^T layout): C[m,n] = sum_k A[m,k] * B[n,k] + bias[n]
// TM x 128 tile, BK=64 (128 B rows = 8 x 16B blocks), 256 threads (4 waves),
// 16x16x32 MFMA. LDS rows XOR-swizzled (slot = blk ^ (row&7)) -> fragment
// ds_read_b128 are conflict-free.
// Config search CLOSED (measured): QKV = TM=128/DB=0 (TM=64 R9: +5us;
// DB=1 R7: neutral). Out-proj = TM=32/DB=1 (TM=64/128 R2/R3: slower;
// DB=1 R6: helps this latency-bound small GEMM).
// XCD-locality swizzle: groups of 8 consecutive linear block IDs share the
// same col-tile. (gridDim.y must be a multiple of 8.)
// MODE 0: fp32 out [M, Ndim] row-major
// MODE 1: QKV epilogue -> bf16 Q,K head-split [B,H,T,Dh] (Q pre-scaled by
//         SCALE_Q); V written TRANSPOSED [B,H,Dh,T] with keys permuted per
//         32-key group (key h*16+g*4+r -> slot g*8+h*4+r) to match the attn
//         16x16 PV MFMA k-slot order.
// ---------------------------------------------------------------------------
template <int MODE, int TM, int DB>
__global__ __launch_bounds__(256) void gemm_bt_kernel(
    const unsigned short* __restrict__ A, const unsigned short* __restrict__ Bm,
    const float* __restrict__ bias, const int Kdim, const int Ndim,
    float* __restrict__ Cout,
    unsigned short* __restrict__ Qo, unsigned short* __restrict__ Ko,
    unsigned short* __restrict__ Vo)
{
    constexpr int IW  = TM / 32;           // acc row-frags per wave
    constexpr int NCH = (TM + 128) / 8;    // 1 KB staging chunks (8 rows each)
    constexpr int TB  = (TM + 128) * 128;  // bytes per LDS buffer
    __shared__ unsigned short Sm[(TM + 128) * 64 * (DB ? 2 : 1)];
    const int tid  = threadIdx.x;
    const int lane = tid & 63, wv = tid >> 6;
    const int l15  = lane & 15, l4 = lane >> 4;
    const int wr   = wv >> 1,  wc = wv & 1;

    // swizzle (gridDim.y must be a multiple of 8)
    const int lin = blockIdx.y * gridDim.x + blockIdx.x;
    const int gx  = (lin >> 3) % gridDim.x;
    const int gy  = (lin / (8 * gridDim.x)) * 8 + (lin & 7);
    const int row0 = gy * TM, col0 = gx * 128;

    auto stage = [&](int k0, int b) {
        #pragma unroll
        for (int ch0 = 0; ch0 < NCH; ch0 += 4) {   // NCH % 4 == 0
            const int ch = ch0 + wv;           // wave-uniform per call
            const int offb = ch * 1024;
            const int off  = offb + lane * 16;
            const int r  = off >> 7;           // row in [0, TM+128)
            const int bl = (off & 127) >> 4;   // 16B block within 128 B row
            const int gc = (bl ^ (r & 7)) << 3;    // swizzled element col
            const unsigned short* src = (r < TM)
                ? A  + (size_t)(row0 + r) * Kdim + k0 + gc
                : Bm + (size_t)(col0 + (r - TM)) * Kdim + k0 + gc;
            async_copy16(src, (char*)Sm + b * TB + offb);
        }
    };

    f32x4 acc[IW][4];
    #pragma unroll
    for (int i = 0; i < IW; ++i)
        #pragma unroll
        for (int j = 0; j < 4; ++j)
            acc[i][j] = (f32x4){0.f, 0.f, 0.f, 0.f};

    if (DB) stage(0, 0);

    for (int k0 = 0, it = 0; k0 < Kdim; k0 += 64, ++it) {
        const int cur = DB ? (it & 1) : 0;
        __syncthreads();                 // DB=0: prev ds_reads done.
                                         // DB=1: buf[cur] staged (vmcnt drain)
                                         //       + buf[cur^1] readers done.
        if (DB) {
            if (k0 + 64 < Kdim) stage(k0 + 64, cur ^ 1);
        } else {
            stage(k0, 0);
            __syncthreads();             // drains vmcnt -> tiles ready
        }
        const char* Sb_ = (const char*)Sm + cur * TB;

        #pragma unroll
        for (int c = 0; c < 2; ++c) {          // k halves of the 64-wide tile
            bf16x8 af[IW], bfr[4];
            #pragma unroll
            for (int i = 0; i < IW; ++i) {
                const int row = wr * (TM / 2) + i * 16 + l15;
                af[i] = *(const bf16x8*)(Sb_ +
                        row * 128 + (((c << 2) + l4) ^ (row & 7)) * 16);
            }
            #pragma unroll
            for (int j = 0; j < 4; ++j) {
                const int row = TM + wc * 64 + j * 16 + l15;
                bfr[j] = *(const bf16x8*)(Sb_ +
                        row * 128 + (((c << 2) + l4) ^ (row & 7)) * 16);
            }
            #pragma unroll
            for (int i = 0; i < IW; ++i)
                #pragma unroll
                for (int j = 0; j < 4; ++j)
                    acc[i][j] = __builtin_amdgcn_mfma_f32_16x16x32_bf16(af[i], bfr[j], acc[i][j], 0, 0, 0);
        }
    }

    // C/D layout: col = lane&15, row = (lane>>4)*4 + reg
    if (MODE == 0) {
        #pragma unroll
        for (int j = 0; j < 4; ++j) {
            const int n = col0 + wc * 64 + j * 16 + l15;
            const float bv_ = bias[n];
            #pragma unroll
            for (int i = 0; i < IW; ++i) {
                #pragma unroll
                for (int r = 0; r < 4; ++r) {
                    const int m = row0 + wr * (TM / 2) + i * 16 + l4 * 4 + r;
                    Cout[(size_t)m * Ndim + n] = acc[i][j][r] + bv_;
                }
            }
        }
    } else {
        #pragma unroll
        for (int j = 0; j < 4; ++j) {
            const int n = col0 + wc * 64 + j * 16 + l15;
            const int which = n / D;           // uniform per block (768 % 128 == 0)
            const int hd = n % D;
            const int h = hd >> 6, d = hd & 63;
            const float bv_ = bias[n];
            if (which == 2) {
                // V transposed [B,H,Dh,T], keys slot-permuted per 32-group:
                // t = h16*16 + g*4 + r  ->  tp = base32 | g*8 + h16*4 + r
                #pragma unroll
                for (int i = 0; i < IW; ++i) {
                    const int m0 = row0 + wr * (TM / 2) + i * 16 + l4 * 4;
                    const int b = m0 >> 11, t = m0 & (T - 1);
                    const int g = (t >> 2) & 3, h16 = (t >> 4) & 1;
                    const int tp = (t & ~31) | (g << 3) | (h16 << 2);
                    float4 v4;
                    v4.x = acc[i][j][0] + bv_; v4.y = acc[i][j][1] + bv_;
                    v4.z = acc[i][j][2] + bv_; v4.w = acc[i][j][3] + bv_;
                    *(ushort4*)&Vo[((size_t)(b * H + h) * Dh + d) * T + tp] = f2bf4(v4);
                }
            } else {
                const float scale = (which == 0) ? SCALE_Q : 1.0f;
                unsigned short* dst = (which == 0) ? Qo : Ko;
                #pragma unroll
                for (int i = 0; i < IW; ++i) {
                    #pragma unroll
                    for (int r = 0; r < 4; ++r) {
                        const int m = row0 + wr * (TM / 2) + i * 16 + l4 * 4 + r;
                        const int b = m >> 11, t = m & (T - 1);
                        dst[((size_t)(b * H + h) * T + t) * Dh + d] =
                            f2bf((acc[i][j][r] + bv_) * scale);
                    }
                }
            }
        }
    }
}

// ---------------------------------------------------------------------------
// Flash attention — proven 16x16 structure + hoisted loop-invariant
// addressing (measured 48.4-48.6 us; best total 155.46 us, R10).
// FROZEN. Evidence across 11 rounds: throughput invariant to waves/CU
// 12->20 (R8 KV-split), worse at 6 (R3 QBLK=128; R11 32x32 2-wave blocks),
// worse with VMEM in the dependency chain (R4/R5 K-from-global), neutral
// to address-VALU hoisting (R10). It is a multi-way local optimum:
// latency/issue-bound with no saturated pipe.
// R11 lesson (do not retry 32x32 MFMA here): the 32x32 A-operand b128 read
// needs 32 DISTINCT 128-B rows per hs-phase -> pigeonhole onto 8 bank
// groups = structural 4-way conflict (measured 3.1M/dispatch), unfixable
// by any XOR swizzle while keeping b128 + global_load_lds staging; and
// 128-thread blocks at grid 768 give only 6 waves/CU.
// ---------------------------------------------------------------------------
__global__ __launch_bounds__(256) void attn_kernel(
    const unsigned short* __restrict__ Q, const unsigned short* __restrict__ Kg,
    const unsigned short* __restrict__ Vt, unsigned short* __restrict__ Ctx)
{
    __shared__ unsigned short Ks[2][64 * 64];
    __shared__ unsigned short Vs[2][64 * 64];
    const int bh = blockIdx.y;
    const int q0 = blockIdx.x * 64;
    const int tid = threadIdx.x, lane = tid & 63, wv = tid >> 6;
    const int l15 = lane & 15, l4 = lane >> 4;
    const unsigned short* Qp = Q  + (size_t)bh * T * Dh;
    const unsigned short* Kp = Kg + (size_t)bh * T * Dh;
    const unsigned short* Vp = Vt + (size_t)bh * Dh * T;

    // Q fragments: [n=q=l15][k = l4*8 + j], chunk c covers dh c*32..+31
    bf16x8 qf[2];
    #pragma unroll
    for (int c = 0; c < 2; ++c)
        qf[c] = *(const bf16x8*)&Qp[(size_t)(q0 + wv * 16 + l15) * Dh + c * 32 + l4 * 8];

    const short oneb = (short)0x3F80;     // bf16 1.0
    const bf16x8 onesf = {oneb, oneb, oneb, oneb, oneb, oneb, oneb, oneb};

    // ---- hoisted loop-invariant addressing ----
    // fragment reads: row = x*16 + l15  =>  row&7 == l15&7 for every row.
    const int rbase = l15 * 128;                     // row byte base within tile
    const int sw0   = (l4 ^ (l15 & 7)) * 16;         // swizzled 16B slot, c/G=0
    const int sw1   = ((4 + l4) ^ (l15 & 7)) * 16;   // swizzled 16B slot, c/G=1
    // staging: per-lane source bases (advance K by kt*64, V by kt)
    const int s_offb0 = wv * 2048;                   // chunk i=0 LDS offset
    const int s_offb1 = wv * 2048 + 1024;            // chunk i=1
    const int s_r0 = (s_offb0 + lane * 16) >> 7;
    const int s_r1 = (s_offb1 + lane * 16) >> 7;
    const int s_gc0 = ((((s_offb0 + lane * 16) & 127) >> 4) ^ (s_r0 & 7)) << 3;
    const int s_gc1 = ((((s_offb1 + lane * 16) & 127) >> 4) ^ (s_r1 & 7)) << 3;
    const unsigned short* ksrc0 = Kp + s_r0 * Dh + s_gc0;
    const unsigned short* ksrc1 = Kp + s_r1 * Dh + s_gc1;
    const unsigned short* vsrc0 = Vp + (size_t)s_r0 * T + s_gc0;
    const unsigned short* vsrc1 = Vp + (size_t)s_r1 * T + s_gc1;

    auto load_tiles = [&](int kt, int buf) {
        async_copy16(ksrc0 + kt * Dh, (char*)&Ks[buf][0] + s_offb0);
        async_copy16(ksrc1 + kt * Dh, (char*)&Ks[buf][0] + s_offb1);
        async_copy16(vsrc0 + kt,      (char*)&Vs[buf][0] + s_offb0);
        async_copy16(vsrc1 + kt,      (char*)&Vs[buf][0] + s_offb1);
    };

    load_tiles(0, 0);
    f32x4 o[4], oL;
    #pragma unroll
    for (int nj = 0; nj < 4; ++nj) o[nj] = (f32x4){0.f, 0.f, 0.f, 0.f};
    oL = (f32x4){0.f, 0.f, 0.f, 0.f};

    for (int kt64 = 0; kt64 < T / 64; ++kt64) {
        const int cur = kt64 & 1;
        __syncthreads();     // K/V(kt64) ready (vmcnt drain); buf cur^1 reads done
        if (kt64 + 1 < T / 64) load_tiles((kt64 + 1) * 64, cur ^ 1);

        // per-buffer fragment base pointers (2 adds each; t/nj*2048 -> imm)
        const char* Kb0 = (const char*)&Ks[cur][0] + rbase + sw0;
        const char* Kb1 = (const char*)&Ks[cur][0] + rbase + sw1;
        const char* Vb0 = (const char*)&Vs[cur][0] + rbase + sw0;
        const char* Vb1 = (const char*)&Vs[cur][0] + rbase + sw1;

        // ---- S^T for k16 tiles 0,1 (keys 0..31) ----
        f32x4 Sa[2] = {(f32x4){0.f,0.f,0.f,0.f}, (f32x4){0.f,0.f,0.f,0.f}};
        #pragma unroll
        for (int t = 0; t < 2; ++t) {
            bf16x8 kb0 = *(const bf16x8*)(Kb0 + t * 2048);
            bf16x8 kb1 = *(const bf16x8*)(Kb1 + t * 2048);
            Sa[t] = __builtin_amdgcn_mfma_f32_16x16x32_bf16(kb0, qf[0], Sa[t], 0, 0, 0);
            Sa[t] = __builtin_amdgcn_mfma_f32_16x16x32_bf16(kb1, qf[1], Sa[t], 0, 0, 0);
        }
        #pragma unroll
        for (int t = 0; t < 2; ++t)
            #pragma unroll
            for (int r = 0; r < 4; ++r)
                Sa[t][r] = __builtin_amdgcn_exp2f(Sa[t][r]);
        union { unsigned u[4]; bf16x8 v; } p0;
        p0.u[0] = permpk(Sa[0][1], Sa[0][0]);
        p0.u[1] = permpk(Sa[0][3], Sa[0][2]);
        p0.u[2] = permpk(Sa[1][1], Sa[1][0]);
        p0.u[3] = permpk(Sa[1][3], Sa[1][2]);

        // ---- S^T for k16 tiles 2,3 (keys 32..63) ----
        f32x4 Sb[2] = {(f32x4){0.f,0.f,0.f,0.f}, (f32x4){0.f,0.f,0.f,0.f}};
        #pragma unroll
        for (int t = 0; t < 2; ++t) {
            bf16x8 kb0 = *(const bf16x8*)(Kb0 + (t + 2) * 2048);
            bf16x8 kb1 = *(const bf16x8*)(Kb1 + (t + 2) * 2048);
            Sb[t] = __builtin_amdgcn_mfma_f32_16x16x32_bf16(kb0, qf[0], Sb[t], 0, 0, 0);
            Sb[t] = __builtin_amdgcn_mfma_f32_16x16x32_bf16(kb1, qf[1], Sb[t], 0, 0, 0);
        }

        // ---- PV G0 (overlaps exp2 G1) ----
        oL = __builtin_amdgcn_mfma_f32_16x16x32_bf16(p0.v, onesf, oL, 0, 0, 0);
        #pragma unroll
        for (int nj = 0; nj < 4; ++nj) {
            bf16x8 vb = *(const bf16x8*)(Vb0 + nj * 2048);
            o[nj] = __builtin_amdgcn_mfma_f32_16x16x32_bf16(p0.v, vb, o[nj], 0, 0, 0);
        }

        #pragma unroll
        for (int t = 0; t < 2; ++t)
            #pragma unroll
            for (int r = 0; r < 4; ++r)
                Sb[t][r] = __builtin_amdgcn_exp2f(Sb[t][r]);
        union { unsigned u[4]; bf16x8 v; } p1;
        p1.u[0] = permpk(Sb[0][1], Sb[0][0]);
        p1.u[1] = permpk(Sb[0][3], Sb[0][2]);
        p1.u[2] = permpk(Sb[1][1], Sb[1][0]);
        p1.u[3] = permpk(Sb[1][3], Sb[1][2]);

        // ---- PV G1 ----
        oL = __builtin_amdgcn_mfma_f32_16x16x32_bf16(p1.v, onesf, oL, 0, 0, 0);
        #pragma unroll
        for (int nj = 0; nj < 4; ++nj) {
            bf16x8 vb = *(const bf16x8*)(Vb1 + nj * 2048);
            o[nj] = __builtin_amdgcn_mfma_f32_16x16x32_bf16(p1.v, vb, o[nj], 0, 0, 0);
        }
    }

    // normalize, write ctx bf16 [B, T, D]
    const int b = bh / H, h = bh % H;
    #pragma unroll
    for (int r = 0; r < 4; ++r) {
        const float inv = 1.0f / oL[r];
        const int t = q0 + wv * 16 + l4 * 4 + r;
        #pragma unroll
        for (int nj = 0; nj < 4; ++nj) {
            const int col = h * 64 + nj * 16 + l15;
            Ctx[(size_t)(b * T + t) * D + col] = f2bf(o[nj][r] * inv);
        }
    }
}

// ---------------------------------------------------------------------------
extern "C" void kernel_launch(void* const* d_in, const int* in_sizes, int n_in,
                              void* d_out, int out_size, void* d_ws, size_t ws_size,
                              hipStream_t stream) {
    const float* x  = (const float*)d_in[0];
    const float* Wq = (const float*)d_in[1];
    const float* bq = (const float*)d_in[2];
    const float* Wk = (const float*)d_in[3];
    const float* bk = (const float*)d_in[4];
    const float* Wv = (const float*)d_in[5];
    const float* bv = (const float*)d_in[6];
    const float* Wo = (const float*)d_in[7];
    const float* bo = (const float*)d_in[8];
    float* out = (float*)d_out;

    // workspace carve-up (~34 MB total)
    char* w = (char*)d_ws;
    auto alloc = [&](size_t bytes) {
        char* p = w; w += (bytes + 255) & ~(size_t)255; return p;
    };
    unsigned short* Xb    = (unsigned short*)alloc((size_t)M * D * 2);
    unsigned short* Wqkvb = (unsigned short*)alloc((size_t)NQKV * D * 2);
    unsigned short* Wob   = (unsigned short*)alloc((size_t)D * D * 2);
    float*          biasS = (float*)alloc((size_t)NQKV * 4);
    unsigned short* Qb    = (unsigned short*)alloc((size_t)M * D * 2);
    unsigned short* Kb    = (unsigned short*)alloc((size_t)M * D * 2);
    unsigned short* Vtb   = (unsigned short*)alloc((size_t)M * D * 2);
    unsigned short* Ctxb  = (unsigned short*)alloc((size_t)M * D * 2);

    // prep: memory-bound, grid-stride; 2048 blocks halves the per-thread
    // iteration count vs 1024 (G11: cap ~2048)
    prep_kernel<<<2048, 256, 0, stream>>>(
        (const float4*)x, (const float4*)Wq, (const float4*)Wk, (const float4*)Wv,
        (const float4*)Wo, bq, bk, bv,
        (ushort4*)Xb, (ushort4*)Wqkvb, (ushort4*)Wob, biasS);

    // QKV GEMM: TM=128, DB=0 (best measured: R6/R10 config; TM=64 R9 and
    // DB=1 R7 both regressed/neutral)
    gemm_bt_kernel<1, 128, 0><<<dim3(NQKV / 128, M / 128), 256, 0, stream>>>(
        Xb, Wqkvb, biasS, D, NQKV, nullptr, Qb, Kb, Vtb);

    // attention: proven kernel (frozen), grid (32, 24) = 768 blocks (3/CU)
    attn_kernel<<<dim3(T / 64, Bb * H), 256, 0, stream>>>(Qb, Kb, Vtb, Ctxb);

    // out-projection: TM=32 + DB=1 (best measured, R6)
    gemm_bt_kernel<0, 32, 1><<<dim3(D / 128, M / 32), 256, 0, stream>>>(
        Ctxb, Wob, bo, D, D, out, nullptr, nullptr, nullptr);
}